// Round 6
// baseline (572.799 us; speedup 1.0000x reference)
//
#include <hip/hip_runtime.h>
#include <cstddef>

typedef float f4 __attribute__((ext_vector_type(4)));

#define OUT_FEATS 4096
#define IN_FEATS  16384
#define NCOL4     (IN_FEATS / 4)   // 4096 float4 per row
#define EPS       1e-8f

#define BT      512                // threads per block (8 waves)
#define KITER   16                 // rows per thread -> 16 x f4 = 64 VGPR payload
#define GROUPS  (BT / 2)           // 256 row-groups per block
#define NBLK    2048               // stripes of 8 columns (2 f4) each

// ---------------------------------------------------------------------------
// Fused single-read kernel, v3. Block b owns 8 columns [8b, 8b+8):
// each thread reads 16 f4 of its stripe ONCE via asm-volatile
// global_load_dwordx4 (cannot be rematerialized, unlike C loads from a
// const __restrict__ arg, which AMDGPU treats as no-clobber and happily
// re-issues -- that is what silently broke rounds 3 and 4). The payload
// stays live in 64 VGPRs across the coeff reduction, then feeds the
// rank-1 apply + nt store. A is read exactly once: 512 MiB total traffic.
//
// Occupancy: __launch_bounds__(512,4) -> <=128 VGPR -> 2 blocks/CU,
// 16 waves/CU. 2048 blocks = 4 generations; adjacent stripes (same XCD
// via chunked swizzle) share 128 B L2 lines, so the 32 B/row segments
// still give full line utilization.
// ---------------------------------------------------------------------------
__global__ void __launch_bounds__(BT, 4)
k_fused(const f4* __restrict__ A4,
        const float* __restrict__ v,
        f4* __restrict__ out) {
    __shared__ float vs[OUT_FEATS];   // staged v (16 KiB)
    __shared__ float red[8];          // per-wave ||v||^2 partials
    __shared__ f4    red2[16];        // 8 waves x 2 col-quads

    // XCD-chunked swizzle: 2048 blocks, 8 XCDs, 256 consecutive stripes/XCD
    const int b = (blockIdx.x & 7) * (NBLK / 8) + (blockIdx.x >> 3);

    const int T = threadIdx.x;
    const int q = T & 1;              // which f4 of the 8-col stripe
    const int g = T >> 1;             // row-group 0..255
    const int w = T >> 6;             // wave id 0..7
    const int c4 = b * 2 + q;         // global float4 column index

    // ---- 1. stage v into LDS + ||v||^2 partials (2 f4 per thread) ----
    float vsq;
    {
        const f4* v4 = (const f4*)v;
        const f4 x0 = v4[T];
        const f4 x1 = v4[T + BT];
        ((f4*)vs)[T]      = x0;
        ((f4*)vs)[T + BT] = x1;
        vsq = x0.x*x0.x + x0.y*x0.y + x0.z*x0.z + x0.w*x0.w
            + x1.x*x1.x + x1.y*x1.y + x1.z*x1.z + x1.w*x1.w;
    }
    #pragma unroll
    for (int off = 32; off > 0; off >>= 1) vsq += __shfl_down(vsq, off, 64);
    if ((T & 63) == 0) red[w] = vsq;

    // ---- 2. payload: 16 exactly-once loads, results pinned in VGPRs ----
    f4 a[KITER];
    const size_t base = (size_t)g * NCOL4 + c4;
    #pragma unroll
    for (int k = 0; k < KITER; ++k) {
        const f4* p = A4 + base + (size_t)k * GROUPS * NCOL4;
        asm volatile("global_load_dwordx4 %0, %1, off"
                     : "=v"(a[k]) : "v"(p));
    }

    __syncthreads();                                   // vs, red ready
    asm volatile("s_waitcnt vmcnt(0)" ::: "memory");   // payload landed
    __builtin_amdgcn_sched_barrier(0);                 // rule #18: no hoisting

    // ---- 3. coeff partial over this thread's 16 rows ----
    f4 s = 0.f;
    #pragma unroll
    for (int k = 0; k < KITER; ++k)
        s += vs[g + GROUPS * k] * a[k];

    // ---- 4. reduce across the 32 lanes/wave sharing this q ----
    #pragma unroll
    for (int off = 2; off <= 32; off <<= 1) {
        s.x += __shfl_xor(s.x, off, 64);
        s.y += __shfl_xor(s.y, off, 64);
        s.z += __shfl_xor(s.z, off, 64);
        s.w += __shfl_xor(s.w, off, 64);
    }
    if ((T & 63) < 2) red2[w * 2 + q] = s;
    __syncthreads();

    // ---- 5. final coeff for this thread's col-quad ----
    float denom = EPS;
    #pragma unroll
    for (int i = 0; i < 8; ++i) denom += red[i];
    f4 cf = red2[q];
    #pragma unroll
    for (int w2 = 1; w2 < 8; ++w2) cf += red2[w2 * 2 + q];
    cf = cf / denom;

    // ---- 6. apply rank-1 update + non-temporal store ----
    #pragma unroll
    for (int k = 0; k < KITER; ++k) {
        const f4 o = a[k] - vs[g + GROUPS * k] * cf;
        __builtin_nontemporal_store(o, &out[base + (size_t)k * GROUPS * NCOL4]);
    }
}

// ---------------------------------------------------------------------------
extern "C" void kernel_launch(void* const* d_in, const int* in_sizes, int n_in,
                              void* d_out, int out_size, void* d_ws, size_t ws_size,
                              hipStream_t stream) {
    const f4*    A4 = (const f4*)d_in[0];     // raw_update [4096, 16384] fp32
    const float* v  = (const float*)d_in[1];  // v [4096] fp32
    f4* out = (f4*)d_out;

    k_fused<<<NBLK, BT, 0, stream>>>(A4, v, out);
}

// Round 7
// 153.741 us; speedup vs baseline: 3.7257x; 3.7257x over previous
//
#include <hip/hip_runtime.h>
#include <cstddef>

typedef float f4 __attribute__((ext_vector_type(4)));

#define OUT_FEATS 4096
#define IN_FEATS  16384
#define NCOL4     (IN_FEATS / 4)   // 4096 float4 per row
#define EPS       1e-8f

// ---------------------------------------------------------------------------
// Kernel 1: split-K partial GEMV. partial[chunk][j] = sum_{r in chunk} v[r]*A[r][j]
// grid = (NCOL4/256, nchunk), block = 256. 8 accumulators, 8 loads in flight.
// Fully coalesced: wave reads 1 KiB contiguous per instr. Normal loads —
// this pass is what makes A resident in the 256 MiB Infinity Cache.
// Row chunks dispatch in increasing order -> high rows are MRU afterwards.
// ---------------------------------------------------------------------------
__global__ void __launch_bounds__(256)
k_gemv(const f4* __restrict__ A4, const float* __restrict__ v,
       f4* __restrict__ partial, int rows_per_chunk) {
    const int col4 = blockIdx.x * 256 + threadIdx.x;
    const int r0 = blockIdx.y * rows_per_chunk;

    f4 acc[8];
    #pragma unroll
    for (int i = 0; i < 8; ++i) acc[i] = 0.f;

    size_t base = (size_t)r0 * NCOL4 + col4;
    #pragma unroll 4
    for (int rr = 0; rr < rows_per_chunk; rr += 8) {
        const f4 a0 = A4[base];
        const f4 a1 = A4[base + (size_t)1 * NCOL4];
        const f4 a2 = A4[base + (size_t)2 * NCOL4];
        const f4 a3 = A4[base + (size_t)3 * NCOL4];
        const f4 a4 = A4[base + (size_t)4 * NCOL4];
        const f4 a5 = A4[base + (size_t)5 * NCOL4];
        const f4 a6 = A4[base + (size_t)6 * NCOL4];
        const f4 a7 = A4[base + (size_t)7 * NCOL4];
        const int r = r0 + rr;
        acc[0] += v[r + 0] * a0;
        acc[1] += v[r + 1] * a1;
        acc[2] += v[r + 2] * a2;
        acc[3] += v[r + 3] * a3;
        acc[4] += v[r + 4] * a4;
        acc[5] += v[r + 5] * a5;
        acc[6] += v[r + 6] * a6;
        acc[7] += v[r + 7] * a7;
        base += (size_t)8 * NCOL4;
    }
    const f4 tot = ((acc[0] + acc[1]) + (acc[2] + acc[3])) +
                   ((acc[4] + acc[5]) + (acc[6] + acc[7]));
    partial[(size_t)blockIdx.y * NCOL4 + col4] = tot;
}

// ---------------------------------------------------------------------------
// Kernel 2: coeff[j] = (sum_c partial[c][j]) / (||v||^2 + eps). 16 blocks.
// ---------------------------------------------------------------------------
__global__ void __launch_bounds__(256)
k_reduce(const f4* __restrict__ partial, const float* __restrict__ v,
         f4* __restrict__ coeff, int nchunk) {
    __shared__ float red[4];
    const int T = threadIdx.x;
    float s = 0.f;
    const f4* v4 = (const f4*)v;
    #pragma unroll
    for (int i = 0; i < OUT_FEATS / 4 / 256; ++i) {
        const f4 x = v4[T + i * 256];
        s += x.x * x.x + x.y * x.y + x.z * x.z + x.w * x.w;
    }
    #pragma unroll
    for (int off = 32; off > 0; off >>= 1) s += __shfl_down(s, off, 64);
    if ((T & 63) == 0) red[T >> 6] = s;
    __syncthreads();
    const float denom = red[0] + red[1] + red[2] + red[3] + EPS;

    const int j4 = blockIdx.x * 256 + T;
    f4 acc = 0.f;
    #pragma unroll 8
    for (int c = 0; c < nchunk; ++c)
        acc += partial[(size_t)c * NCOL4 + j4];
    coeff[j4] = acc / denom;
}

// ---------------------------------------------------------------------------
// Kernel 3: out = A - v[i]*coeff[j].
// REVERSE row traversal: first-dispatched blocks take the highest rows —
// the ones GEMV read most recently (MRU in the Infinity Cache) — so A-reads
// hit MALL instead of HBM even while out-writes evict the LRU (low-row)
// entries. nt stores additionally mark the out stream evict-first so it
// doesn't displace A. 8 loads + 8 coeff loads in flight per step.
// ---------------------------------------------------------------------------
#define AROWS 4
__global__ void __launch_bounds__(256)
k_apply(const f4* __restrict__ A4, const float* __restrict__ v,
        const f4* __restrict__ coeff, f4* __restrict__ out) {
    const int T = threadIdx.x;
    const int r0 = ((int)gridDim.x - 1 - (int)blockIdx.x) * AROWS;
    #pragma unroll
    for (int r = 0; r < AROWS; ++r) {
        const int row = r0 + r;
        const float vr = v[row];
        const size_t base = (size_t)row * NCOL4 + T;
        #pragma unroll
        for (int j0 = 0; j0 < NCOL4 / 256; j0 += 8) {
            f4 a[8], c[8];
            #pragma unroll
            for (int u = 0; u < 8; ++u) a[u] = A4[base + (size_t)(j0 + u) * 256];
            #pragma unroll
            for (int u = 0; u < 8; ++u) c[u] = coeff[T + (j0 + u) * 256];
            #pragma unroll
            for (int u = 0; u < 8; ++u)
                __builtin_nontemporal_store(a[u] - vr * c[u],
                                            &out[base + (size_t)(j0 + u) * 256]);
        }
    }
}

// ---------------------------------------------------------------------------
extern "C" void kernel_launch(void* const* d_in, const int* in_sizes, int n_in,
                              void* d_out, int out_size, void* d_ws, size_t ws_size,
                              hipStream_t stream) {
    const f4*    A4 = (const f4*)d_in[0];     // raw_update [4096, 16384] fp32
    const float* v  = (const float*)d_in[1];  // v [4096] fp32
    f4* out = (f4*)d_out;

    // ws layout (floats): [0, 16384) coeff | [16384, ...) partials
    float* ws = (float*)d_ws;
    f4* coeff   = (f4*)ws;
    f4* partial = (f4*)(ws + IN_FEATS);

    const size_t avail_floats = ws_size / sizeof(float);
    int nchunk = 64;
    while (nchunk > 8 &&
           (size_t)IN_FEATS + (size_t)nchunk * IN_FEATS > avail_floats) {
        nchunk >>= 1;
    }
    const int rows_per_chunk = OUT_FEATS / nchunk;   // >= 64, divisible by 8

    dim3 g1(NCOL4 / 256, nchunk);
    k_gemv<<<g1, 256, 0, stream>>>(A4, v, partial, rows_per_chunk);

    k_reduce<<<NCOL4 / 256, 256, 0, stream>>>(partial, v, coeff, nchunk);

    k_apply<<<OUT_FEATS / AROWS, 256, 0, stream>>>(A4, v, coeff, out);
}

// Round 9
// 117.720 us; speedup vs baseline: 4.8658x; 1.3060x over previous
//
#include <hip/hip_runtime.h>
#include <cstddef>

typedef float f4 __attribute__((ext_vector_type(4)));

#define OUT_FEATS 4096
#define IN_FEATS  16384
#define NCOL4     (IN_FEATS / 4)   // 4096 float4 per row
#define EPS       1e-8f

#define BT   256                   // threads per block (4 waves)
#define SW8  8                     // stripe width in f4 (32 floats = 128 B)
#define NBLK (NCOL4 / SW8)         // 512 blocks, 2 per CU
#define RG   (BT / SW8)            // 32 row-groups
#define KPT  (OUT_FEATS / RG)      // 128 rows per thread

// ---------------------------------------------------------------------------
// Fully self-contained column-stripe kernel — NO grid sync needed.
// Block b owns columns [32b, 32b+32). coeff[j] for those columns depends
// only on column j of A, so the block:
//   phase 1: streams its stripe (4096 rows x 128 B) computing coeff partials
//   phase 2: LDS tree-reduce -> coeff for its 32 columns (plus local denom)
//   phase 3: re-streams the stripe IN REVERSE row order (MRU-first, so the
//            re-read chases phase 1's Infinity-Cache footprint) applying
//            out = A - v[i]*coeff[j], with nt stores so the 256 MiB out
//            stream doesn't evict A from MALL.
// Access pattern: per wave-load, 8 rows x 128 B contiguous segments = 8
// cachelines/instr — identical line count to a fully-coalesced 1 KiB load.
// (The round-3/6 failures were 64 B / 32 B segments = 16/32 lines per load.)
// No partials in ws, no reduce kernel, no kernel-boundary bubbles.
// ---------------------------------------------------------------------------
__global__ void __launch_bounds__(BT)
k_fused(const f4* __restrict__ A4,
        const float* __restrict__ v,
        f4* __restrict__ out) {
    __shared__ float vs[OUT_FEATS];   // staged v (16 KiB)
    __shared__ f4    red[BT];         // coeff reduction tree (4 KiB)
    __shared__ float dred[4];         // per-wave ||v||^2 partials
    __shared__ f4    cfl[SW8];        // final coeff slice (32 cols)

    const int T = threadIdx.x;
    const int q = T & (SW8 - 1);      // f4-column within stripe 0..7
    const int g = T >> 3;             // row-group 0..31
    const int c4 = blockIdx.x * SW8 + q;

    // ---- stage v into LDS + ||v||^2 ----
    float vsq = 0.f;
    {
        const f4* v4 = (const f4*)v;
        #pragma unroll
        for (int i = 0; i < OUT_FEATS / 4 / BT; ++i) {   // 4 iters
            const f4 x = v4[T + i * BT];
            ((f4*)vs)[T + i * BT] = x;
            vsq += x.x * x.x + x.y * x.y + x.z * x.z + x.w * x.w;
        }
    }
    #pragma unroll
    for (int off = 32; off > 0; off >>= 1) vsq += __shfl_down(vsq, off, 64);
    if ((T & 63) == 0) dred[T >> 6] = vsq;
    __syncthreads();
    const float denom = dred[0] + dred[1] + dred[2] + dred[3] + EPS;

    // ---- phase 1: GEMV over own stripe (forward, 8 loads in flight) ----
    // thread's rows: r = g + 32*k, k = 0..127
    f4 acc[8];
    #pragma unroll
    for (int u = 0; u < 8; ++u) acc[u] = 0.f;

    const size_t base = (size_t)g * NCOL4 + c4;
    for (int k = 0; k < KPT; k += 8) {
        f4 a[8];
        #pragma unroll
        for (int u = 0; u < 8; ++u)
            a[u] = A4[base + (size_t)(k + u) * RG * NCOL4];
        #pragma unroll
        for (int u = 0; u < 8; ++u)
            acc[u] += vs[g + (k + u) * RG] * a[u];   // broadcast LDS read
    }
    const f4 s = ((acc[0] + acc[1]) + (acc[2] + acc[3])) +
                 ((acc[4] + acc[5]) + (acc[6] + acc[7]));

    // ---- phase 2: reduce across the 32 row-groups sharing a column ----
    red[T] = s;
    __syncthreads();
    #pragma unroll
    for (int s2 = RG / 2; s2 >= 1; s2 >>= 1) {
        if (g < s2) red[T] += red[T + s2 * SW8];
        __syncthreads();
    }
    if (T < SW8) cfl[T] = red[T] / denom;
    __syncthreads();
    const f4 cf = cfl[q];

    // ---- phase 3: apply + nt store, REVERSED row order (MRU-first) ----
    for (int k = KPT - 8; k >= 0; k -= 8) {
        f4 a[8];
        #pragma unroll
        for (int u = 0; u < 8; ++u)
            a[u] = A4[base + (size_t)(k + 7 - u) * RG * NCOL4];
        #pragma unroll
        for (int u = 0; u < 8; ++u) {
            const int kk = k + 7 - u;
            const f4 o = a[u] - vs[g + kk * RG] * cf;
            __builtin_nontemporal_store(o, &out[base + (size_t)kk * RG * NCOL4]);
        }
    }
}

// ---------------------------------------------------------------------------
extern "C" void kernel_launch(void* const* d_in, const int* in_sizes, int n_in,
                              void* d_out, int out_size, void* d_ws, size_t ws_size,
                              hipStream_t stream) {
    const f4*    A4 = (const f4*)d_in[0];     // raw_update [4096, 16384] fp32
    const float* v  = (const float*)d_in[1];  // v [4096] fp32
    f4* out = (f4*)d_out;

    k_fused<<<NBLK, BT, 0, stream>>>(A4, v, out);
}

// Round 10
// 116.019 us; speedup vs baseline: 4.9371x; 1.0147x over previous
//
#include <hip/hip_runtime.h>
#include <cstddef>

typedef float f4 __attribute__((ext_vector_type(4)));

#define OUT_FEATS 4096
#define IN_FEATS  16384
#define NCOL4     (IN_FEATS / 4)   // 4096 float4 per row
#define EPS       1e-8f

#define BT   256                   // threads per block (4 waves)
#define SW8  8                     // stripe width in f4 (32 floats = 128 B)
#define NBLK (NCOL4 / SW8)         // 512 blocks, 2 per CU
#define RG   (BT / SW8)            // 32 row-groups
#define KPT  (OUT_FEATS / RG)      // 128 rows per thread

// ---------------------------------------------------------------------------
// Self-contained column-stripe kernel (round-9 structure) + software
// pipelining. Block b owns columns [32b, 32b+32):
//   phase 1: stream stripe (4096 x 128 B) -> coeff partials, double-batch
//            pipeline (pa/pb) so 8-16 loads stay in flight continuously;
//            first two batches issued BEFORE the v-staging barrier.
//   phase 2: 3 x shfl_xor in-wave reduce + one 32-entry LDS round, single
//            barrier; every thread computes its own coeff.
//   phase 3: reverse-order apply (MRU-first chases phase 1's MALL
//            footprint; nt stores keep out from evicting A). The last two
//            phase-1 batches (rows 112..127) are still live in pa/pb and
//            are stored WITHOUT re-reading; the pipeline refills behind.
// Wave-load = 8 rows x 128 B = 8 cachelines/instr (same as fully coalesced).
// ---------------------------------------------------------------------------
__global__ void __launch_bounds__(BT)
k_fused(const f4* __restrict__ A4,
        const float* __restrict__ v,
        f4* __restrict__ out) {
    __shared__ float vs[OUT_FEATS];   // staged v (16 KiB)
    __shared__ f4    red[32];         // 4 waves x 8 col-slots
    __shared__ float dred[4];         // per-wave ||v||^2 partials

    const int T = threadIdx.x;
    const int q = T & (SW8 - 1);      // f4-column within stripe 0..7
    const int g = T >> 3;             // row-group 0..31
    const int w = T >> 6;             // wave 0..3
    const int c4 = blockIdx.x * SW8 + q;

    const size_t base = (size_t)g * NCOL4 + c4;
#define ROWOFF(k) (base + (size_t)(k) * RG * NCOL4)

    // ---- issue first two A-batches before anything else (HBM busy early) --
    f4 pa[8], pb[8];
    #pragma unroll
    for (int u = 0; u < 8; ++u) pa[u] = A4[ROWOFF(u)];
    #pragma unroll
    for (int u = 0; u < 8; ++u) pb[u] = A4[ROWOFF(8 + u)];

    // ---- stage v into LDS + ||v||^2 ----
    float vsq = 0.f;
    {
        const f4* v4 = (const f4*)v;
        #pragma unroll
        for (int i = 0; i < OUT_FEATS / 4 / BT; ++i) {   // 4 iters
            const f4 x = v4[T + i * BT];
            ((f4*)vs)[T + i * BT] = x;
            vsq += x.x * x.x + x.y * x.y + x.z * x.z + x.w * x.w;
        }
    }
    #pragma unroll
    for (int off = 32; off > 0; off >>= 1) vsq += __shfl_down(vsq, off, 64);
    if ((T & 63) == 0) dred[w] = vsq;
    __syncthreads();
    const float denom = dred[0] + dred[1] + dred[2] + dred[3] + EPS;

    // ---- phase 1: pipelined GEMV over own stripe ----
    f4 acc[8];
    #pragma unroll
    for (int u = 0; u < 8; ++u) acc[u] = 0.f;

    #pragma unroll
    for (int k = 0; k < KPT; k += 16) {
        #pragma unroll
        for (int u = 0; u < 8; ++u)
            acc[u] += vs[g + (k + u) * RG] * pa[u];        // consume batch k
        if (k + 16 < KPT) {
            #pragma unroll
            for (int u = 0; u < 8; ++u) pa[u] = A4[ROWOFF(k + 16 + u)];
        }
        #pragma unroll
        for (int u = 0; u < 8; ++u)
            acc[u] += vs[g + (k + 8 + u) * RG] * pb[u];    // consume batch k+8
        if (k + 24 < KPT) {
            #pragma unroll
            for (int u = 0; u < 8; ++u) pb[u] = A4[ROWOFF(k + 24 + u)];
        }
    }
    // after loop: pa = rows [112..119], pb = rows [120..127] (still live)
    f4 s = ((acc[0] + acc[1]) + (acc[2] + acc[3])) +
           ((acc[4] + acc[5]) + (acc[6] + acc[7]));

    // ---- phase 2: in-wave reduce (g-bits 3..5) + one LDS round ----
    #pragma unroll
    for (int off = 8; off <= 32; off <<= 1) {
        s.x += __shfl_xor(s.x, off, 64);
        s.y += __shfl_xor(s.y, off, 64);
        s.z += __shfl_xor(s.z, off, 64);
        s.w += __shfl_xor(s.w, off, 64);
    }
    if ((T & 63) < 8) red[w * 8 + (T & 7)] = s;
    __syncthreads();
    const f4 cf = (red[q] + red[q + 8] + red[q + 16] + red[q + 24]) / denom;

    // ---- phase 3: reverse-order apply + nt stores, pipelined ----
    // pb = rows [120..127] stored first (no re-read), pa = rows [112..119].
    #pragma unroll
    for (int k = KPT - 8; k >= 8; k -= 16) {
        #pragma unroll
        for (int u = 0; u < 8; ++u) {
            const int kk = k + u;
            __builtin_nontemporal_store(pb[u] - vs[g + kk * RG] * cf,
                                        &out[ROWOFF(kk)]);
        }
        if (k - 16 >= 0) {
            #pragma unroll
            for (int u = 0; u < 8; ++u) pb[u] = A4[ROWOFF(k - 16 + u)];
        }
        #pragma unroll
        for (int u = 0; u < 8; ++u) {
            const int kk = k - 8 + u;
            __builtin_nontemporal_store(pa[u] - vs[g + kk * RG] * cf,
                                        &out[ROWOFF(kk)]);
        }
        if (k - 24 >= 0) {
            #pragma unroll
            for (int u = 0; u < 8; ++u) pa[u] = A4[ROWOFF(k - 24 + u)];
        }
    }
#undef ROWOFF
}

// ---------------------------------------------------------------------------
extern "C" void kernel_launch(void* const* d_in, const int* in_sizes, int n_in,
                              void* d_out, int out_size, void* d_ws, size_t ws_size,
                              hipStream_t stream) {
    const f4*    A4 = (const f4*)d_in[0];     // raw_update [4096, 16384] fp32
    const float* v  = (const float*)d_in[1];  // v [4096] fp32
    f4* out = (f4*)d_out;

    k_fused<<<NBLK, BT, 0, stream>>>(A4, v, out);
}